// Round 1
// 61.275 us; speedup vs baseline: 1.0825x; 1.0825x over previous
//
#include <hip/hip_runtime.h>

#define NAG 128   // num agents
#define TT  100   // timesteps
#define NC  5     // circles per vehicle

// One block per (timestep, scene). Each block:
//   A) zero-fills its scene's g x 128 output rows (coalesced float4)
//   B) stages the scene's circle centers/radii in LDS
//   C) computes the dense g x g intra-scene pair matrix with full lane
//      utilization (every lane holds a valid same-scene pair)
// Scene ranges reproduce searchsorted(ptr[1:], a, 'right') exactly:
//   scene 0      = [0,        ptr[1])
//   scene s      = [ptr[s],   ptr[s+1])   for 1 <= s <= n_ptr-2
//   scene last   = [ptr[last], NAG)
__global__ __launch_bounds__(256) void vehcoll_kernel(
    const float* __restrict__ traj,     // (NAG, TT, 4)
    const float* __restrict__ veh_att,  // (NAG, 2)
    const int*   __restrict__ ptr,      // (n_ptr,)
    float* __restrict__ out,            // TT*NAG*NAG penalties + 1 scalar
    int n_ptr)
{
    __shared__ float s_cx[NC][NAG];
    __shared__ float s_cy[NC][NAG];
    __shared__ float s_rad[NAG];

    const int t   = blockIdx.x;
    const int s   = blockIdx.y;
    const int tid = threadIdx.x;

    // ---- num_pairs scalar (last element) ----
    if (t == 0 && s == 0 && tid == 0) {
        int np = 0;
        for (int k = 0; k + 1 < n_ptr; ++k) {
            int gg = ptr[k + 1] - ptr[k];
            np += gg * gg - gg;
        }
        out[(size_t)TT * NAG * NAG] = (float)np;
    }

    // ---- scene row range [a0, a1) ----
    int a0 = (s == 0) ? 0 : ptr[s];
    int a1 = (s == n_ptr - 1) ? NAG : ptr[s + 1];
    a0 = min(max(a0, 0), NAG);
    a1 = min(max(a1, a0), NAG);
    const int g = a1 - a0;
    if (g <= 0) return;

    float* rowbase = out + (size_t)t * NAG * NAG + (size_t)a0 * NAG;

    // ---- phase A: zero-fill the g x 128 block of rows (coalesced) ----
    const int nvec = g * (NAG / 4);
    float4 z = make_float4(0.f, 0.f, 0.f, 0.f);
    for (int u = tid; u < nvec; u += 256)
        ((float4*)rowbase)[u] = z;

    // ---- phase B: stage this scene's circles into LDS ----
    if (tid < g) {
        const int a = a0 + tid;
        float4 tr = *(const float4*)(traj + ((size_t)a * TT + t) * 4);
        float len = veh_att[a * 2 + 0];
        float wid = veh_att[a * 2 + 1];
        float rad  = 0.5f * wid;
        float cmin = rad - 0.5f * len;          // -half_len + rad
        float step = 0.25f * (len - wid);       // (cmax-cmin)/4
        float inv  = 1.0f / sqrtf(tr.z * tr.z + tr.w * tr.w);
        float hx = tr.z * inv, hy = tr.w * inv;
        #pragma unroll
        for (int c = 0; c < NC; ++c) {
            float cx = cmin + step * (float)c;
            s_cx[c][tid] = tr.x + cx * hx;
            s_cy[c][tid] = tr.y + cx * hy;
        }
        s_rad[tid] = rad;
    }
    __syncthreads();   // orders zero-fill stores + LDS staging vs phase C

    // ---- phase C: dense g x g intra-scene pairs ----
    const int npair = g * g;
    for (int p = tid; p < npair; p += 256) {
        const int li = p / g;
        const int lj = p - li * g;
        if (li == lj) continue;                 // diagonal stays zero

        float ixr[NC], iyr[NC], jxr[NC], jyr[NC];
        #pragma unroll
        for (int c = 0; c < NC; ++c) {
            ixr[c] = s_cx[c][li];  iyr[c] = s_cy[c][li];   // broadcast
            jxr[c] = s_cx[c][lj];  jyr[c] = s_cy[c][lj];   // conflict-free
        }

        float minsq = 3.4e38f;
        #pragma unroll
        for (int ci = 0; ci < NC; ++ci) {
            #pragma unroll
            for (int cj = 0; cj < NC; ++cj) {
                float dx = ixr[ci] - jxr[cj];
                float dy = iyr[ci] - jyr[cj];
                minsq = fminf(minsq, dx * dx + dy * dy);
            }
        }
        float d  = sqrtf(minsq);                // min dist == sqrt(min sq)
        float pd = s_rad[li] + s_rad[lj];       // BUFFER_DIST = 0
        float pen = (d <= pd) ? 1.0f - d / pd : 0.0f;
        rowbase[li * NAG + a0 + lj] = pen;
    }
}

extern "C" void kernel_launch(void* const* d_in, const int* in_sizes, int n_in,
                              void* d_out, int out_size, void* d_ws, size_t ws_size,
                              hipStream_t stream) {
    const float* traj    = (const float*)d_in[0];
    const float* veh_att = (const float*)d_in[1];
    const int*   ptr     = (const int*)d_in[2];
    float*       out     = (float*)d_out;
    const int n_ptr = in_sizes[2];

    dim3 grid(TT, n_ptr > 0 ? n_ptr : 1);
    dim3 block(256);
    hipLaunchKernelGGL(vehcoll_kernel, grid, block, 0, stream,
                       traj, veh_att, ptr, out, n_ptr);
}